// Round 1
// baseline (371.999 us; speedup 1.0000x reference)
//
#include <hip/hip_runtime.h>
#include <hip/hip_bf16.h>
#include <float.h>
#include <math.h>

#define N 4096
#define DIN 64

typedef __bf16 bf16_t;
typedef __bf16 bf16x2 __attribute__((ext_vector_type(2)));
typedef __bf16 bf16x8 __attribute__((ext_vector_type(8)));
typedef float f32x4 __attribute__((ext_vector_type(4)));

// ---------- async global->LDS, 16B per lane ----------
__device__ __forceinline__ void gload16(const void* g, void* l) {
    __builtin_amdgcn_global_load_lds((const __attribute__((address_space(1))) void*)g,
                                     (__attribute__((address_space(3))) void*)l,
                                     16, 0, 0);
}

__device__ __forceinline__ float block_reduce_sum(float s) {
    __shared__ float red[4];
    #pragma unroll
    for (int off = 32; off; off >>= 1) s += __shfl_down(s, off);
    if ((threadIdx.x & 63) == 0) red[threadIdx.x >> 6] = s;
    __syncthreads();
    return red[0] + red[1] + red[2] + red[3];
}

// ---------- K1: rowsums of A -> dinv = 1/sqrt(d) ----------
__global__ __launch_bounds__(256) void k_rowsum_dinv(const float* __restrict__ A,
                                                     float* __restrict__ dinv) {
    int row = blockIdx.x, tid = threadIdx.x;
    const float4* a4 = (const float4*)(A + (size_t)row * N);
    float s = 0.f;
    for (int j = tid; j < N / 4; j += 256) {
        float4 v = a4[j];
        s += v.x + v.y + v.z + v.w;
    }
    float tot = block_reduce_sum(s);
    if (tid == 0) dinv[row] = rsqrtf(tot);
}

// ---------- K2: Sb = bf16(S), Tb = bf16(S^T)  (64x64 LDS transpose tiles) ----------
__global__ __launch_bounds__(256) void k_make_sbt(const float* __restrict__ A,
                                                  const float* __restrict__ dinv,
                                                  bf16_t* __restrict__ Sb,
                                                  bf16_t* __restrict__ Tb) {
    __shared__ float tile[64][65];
    int tid = threadIdx.x;
    int p = tid & 31;   // column-pair index
    int tg = tid >> 5;  // 0..7
    int i0 = blockIdx.y * 64;
    int j0 = blockIdx.x * 64;
    float dj0 = dinv[j0 + 2 * p];
    float dj1 = dinv[j0 + 2 * p + 1];
    #pragma unroll
    for (int rr = 0; rr < 8; rr++) {
        int r = tg + 8 * rr;
        int row = i0 + r;
        float di = dinv[row];
        float2 av = *(const float2*)(A + (size_t)row * N + j0 + 2 * p);
        float v0 = av.x * di * dj0;
        float v1 = av.y * di * dj1;
        bf16x2 bv;
        bv[0] = (bf16_t)v0;
        bv[1] = (bf16_t)v1;
        *(bf16x2*)(Sb + (size_t)row * N + j0 + 2 * p) = bv;
        tile[r][2 * p] = v0;
        tile[r][2 * p + 1] = v1;
    }
    __syncthreads();
    #pragma unroll
    for (int cc = 0; cc < 8; cc++) {
        int c = tg + 8 * cc;
        int gj = j0 + c;
        bf16x2 bv;
        bv[0] = (bf16_t)tile[2 * p][c];
        bv[1] = (bf16_t)tile[2 * p + 1][c];
        *(bf16x2*)(Tb + (size_t)gj * N + i0 + 2 * p) = bv;
    }
}

// ---------- K3: S2 = Sb @ Sb (NT gemm vs Tb), f32 out. m97-style 128x128/BK=32 ----------
__global__ __launch_bounds__(256) void k_gemm(const bf16_t* __restrict__ Sb,
                                              const bf16_t* __restrict__ Tb,
                                              float* __restrict__ S2) {
    __shared__ bf16_t As[128 * 32];
    __shared__ bf16_t Bs[128 * 32];
    int tid = threadIdx.x;
    int lane = tid & 63;
    int wave = tid >> 6;
    int wr = wave >> 1, wc = wave & 1;
    int bi = blockIdx.x, bj = blockIdx.y;

    // staging: chunk c covers (row=c>>2, kchunk=c&3) of the 128x32 tile; 16B per chunk
    int c0 = tid, c1 = tid + 256;
    const bf16_t* Ag0 = Sb + (size_t)(bi * 128 + (c0 >> 2)) * N + (c0 & 3) * 8;
    const bf16_t* Ag1 = Sb + (size_t)(bi * 128 + (c1 >> 2)) * N + (c1 & 3) * 8;
    const bf16_t* Bg0 = Tb + (size_t)(bj * 128 + (c0 >> 2)) * N + (c0 & 3) * 8;
    const bf16_t* Bg1 = Tb + (size_t)(bj * 128 + (c1 >> 2)) * N + (c1 & 3) * 8;
    bf16_t* Al0 = As + c0 * 8;
    bf16_t* Al1 = As + c1 * 8;
    bf16_t* Bl0 = Bs + c0 * 8;
    bf16_t* Bl1 = Bs + c1 * 8;

    f32x4 acc[4][4];
    f32x4 z = {0.f, 0.f, 0.f, 0.f};
    #pragma unroll
    for (int i = 0; i < 4; i++)
        #pragma unroll
        for (int j = 0; j < 4; j++) acc[i][j] = z;

    int r = lane & 15, q = lane >> 4;
    int aoff = (wr * 64 + r) * 32 + q * 8;
    int boff = (wc * 64 + r) * 32 + q * 8;

    for (int k0 = 0; k0 < N; k0 += 32) {
        __syncthreads();
        gload16(Ag0 + k0, Al0);
        gload16(Ag1 + k0, Al1);
        gload16(Bg0 + k0, Bl0);
        gload16(Bg1 + k0, Bl1);
        __syncthreads();
        bf16x8 af[4], bfr[4];
        #pragma unroll
        for (int mi = 0; mi < 4; mi++) af[mi] = *(const bf16x8*)(As + aoff + mi * 16 * 32);
        #pragma unroll
        for (int ni = 0; ni < 4; ni++) bfr[ni] = *(const bf16x8*)(Bs + boff + ni * 16 * 32);
        #pragma unroll
        for (int mi = 0; mi < 4; mi++)
            #pragma unroll
            for (int ni = 0; ni < 4; ni++)
                acc[mi][ni] = __builtin_amdgcn_mfma_f32_16x16x32_bf16(af[mi], bfr[ni],
                                                                      acc[mi][ni], 0, 0, 0);
    }

    // C/D layout: col = lane&15, row = (lane>>4)*4 + reg   [m89-verified]
    int col = lane & 15, row4 = (lane >> 4) * 4;
    #pragma unroll
    for (int mi = 0; mi < 4; mi++) {
        #pragma unroll
        for (int ni = 0; ni < 4; ni++) {
            size_t gi = (size_t)(bi * 128 + wr * 64 + mi * 16 + row4);
            int gj = bj * 128 + wc * 64 + ni * 16 + col;
            float* o = S2 + gi * N + gj;
            #pragma unroll
            for (int rr = 0; rr < 4; rr++) o[(size_t)rr * N] = acc[mi][ni][rr];
        }
    }
}

// ---------- K4: rowsums of P -> dinv2 ----------
__global__ __launch_bounds__(256) void k_rowsum2(const float* __restrict__ A,
                                                 const float* __restrict__ S2,
                                                 const float* __restrict__ dinv,
                                                 const float* __restrict__ theta,
                                                 float* __restrict__ dinv2) {
    int row = blockIdx.x, tid = threadIdx.x;
    float t0 = 1.f / (1.f + expf(-theta[0]));
    float t1 = 1.f / (1.f + expf(-theta[1]));
    float di = dinv[row];
    const float4* a4 = (const float4*)(A + (size_t)row * N);
    const float4* s4 = (const float4*)(S2 + (size_t)row * N);
    const float4* d4 = (const float4*)dinv;
    float s = 0.f;
    for (int j = tid; j < N / 4; j += 256) {
        float4 av = a4[j], sv = s4[j], dv = d4[j];
        s += t0 * di * (av.x * dv.x + av.y * dv.y + av.z * dv.z + av.w * dv.w) +
             t1 * (sv.x + sv.y + sv.z + sv.w);
    }
    float tot = block_reduce_sum(s);
    if (tid == 0) dinv2[row] = rsqrtf(1.f + tot);  // +1 for the identity diagonal
}

// ---------- K5: per-row top-4 of P_ij * dinv2_j (ties -> lower index) ----------
__device__ __forceinline__ bool better(float v1, int j1, float v2, int j2) {
    return v1 > v2 || (v1 == v2 && j1 < j2);
}
__device__ __forceinline__ void ins4(float v, int j, float bv[4], int bj[4]) {
    if (!better(v, j, bv[3], bj[3])) return;
    bv[3] = v; bj[3] = j;
    if (better(bv[3], bj[3], bv[2], bj[2])) {
        float tv = bv[2]; int tj = bj[2]; bv[2] = bv[3]; bj[2] = bj[3]; bv[3] = tv; bj[3] = tj;
    }
    if (better(bv[2], bj[2], bv[1], bj[1])) {
        float tv = bv[1]; int tj = bj[1]; bv[1] = bv[2]; bj[1] = bj[2]; bv[2] = tv; bj[2] = tj;
    }
    if (better(bv[1], bj[1], bv[0], bj[0])) {
        float tv = bv[0]; int tj = bj[0]; bv[0] = bv[1]; bj[0] = bj[1]; bv[1] = tv; bj[1] = tj;
    }
}

__global__ __launch_bounds__(256) void k_topk(const float* __restrict__ A,
                                              const float* __restrict__ S2,
                                              const float* __restrict__ dinv,
                                              const float* __restrict__ dinv2,
                                              const float* __restrict__ theta,
                                              float* __restrict__ topv,
                                              int* __restrict__ topj) {
    int row = blockIdx.x, tid = threadIdx.x;
    float t0 = 1.f / (1.f + expf(-theta[0]));
    float t1 = 1.f / (1.f + expf(-theta[1]));
    float di = dinv[row];
    const float4* a4 = (const float4*)(A + (size_t)row * N);
    const float4* s4 = (const float4*)(S2 + (size_t)row * N);
    const float4* d4 = (const float4*)dinv;
    const float4* dd4 = (const float4*)dinv2;

    float bv[4] = {-FLT_MAX, -FLT_MAX, -FLT_MAX, -FLT_MAX};
    int bj[4] = {N, N, N, N};

    for (int qi = tid; qi < N / 4; qi += 256) {
        float4 av = a4[qi], sv = s4[qi], dv = d4[qi], ddv = dd4[qi];
        int j = 4 * qi;
        float p0 = t0 * av.x * di * dv.x + t1 * sv.x + ((j + 0 == row) ? 1.f : 0.f);
        float p1 = t0 * av.y * di * dv.y + t1 * sv.y + ((j + 1 == row) ? 1.f : 0.f);
        float p2 = t0 * av.z * di * dv.z + t1 * sv.z + ((j + 2 == row) ? 1.f : 0.f);
        float p3 = t0 * av.w * di * dv.w + t1 * sv.w + ((j + 3 == row) ? 1.f : 0.f);
        ins4(p0 * ddv.x, j + 0, bv, bj);
        ins4(p1 * ddv.y, j + 1, bv, bj);
        ins4(p2 * ddv.z, j + 2, bv, bj);
        ins4(p3 * ddv.w, j + 3, bv, bj);
    }

    __shared__ float svv[1024];
    __shared__ int sjj[1024];
    #pragma unroll
    for (int c = 0; c < 4; c++) { svv[tid * 4 + c] = bv[c]; sjj[tid * 4 + c] = bj[c]; }
    for (int s = 128; s > 0; s >>= 1) {
        __syncthreads();
        if (tid < s) {
            #pragma unroll
            for (int c = 0; c < 4; c++) ins4(svv[(tid + s) * 4 + c], sjj[(tid + s) * 4 + c], bv, bj);
            #pragma unroll
            for (int c = 0; c < 4; c++) { svv[tid * 4 + c] = bv[c]; sjj[tid * 4 + c] = bj[c]; }
        }
    }
    if (tid == 0) {
        float sc = dinv2[row];
        #pragma unroll
        for (int c = 0; c < 4; c++) {
            topv[row * 4 + c] = bv[c] * sc;  // full S value: dinv2_i * P_ij * dinv2_j
            topj[row * 4 + c] = bj[c];
        }
    }
}

// ---------- K6: out = (S_masked @ x) @ W^T + b ----------
__global__ __launch_bounds__(64) void k_out(const float* __restrict__ x,
                                            const float* __restrict__ W,
                                            const float* __restrict__ bvec,
                                            const float* __restrict__ topv,
                                            const int* __restrict__ topj,
                                            const int* __restrict__ kin,
                                            float* __restrict__ out) {
    int row = blockIdx.x, lane = threadIdx.x;
    int kk = kin[0];
    if (kk > 4) kk = 4;
    __shared__ float y[DIN];
    float acc = 0.f;
    for (int c = 0; c < kk; c++) {
        float v = topv[row * 4 + c];
        int j = topj[row * 4 + c];
        acc += v * x[(size_t)j * DIN + lane];
    }
    y[lane] = acc;
    __syncthreads();
    const float4* w4 = (const float4*)(W + (size_t)lane * DIN);
    const float4* y4 = (const float4*)y;
    float o = bvec[lane];
    #pragma unroll
    for (int d = 0; d < DIN / 4; d++) {
        float4 wv = w4[d], yv = y4[d];
        o += wv.x * yv.x + wv.y * yv.y + wv.z * yv.z + wv.w * yv.w;
    }
    out[(size_t)row * DIN + lane] = o;
}

extern "C" void kernel_launch(void* const* d_in, const int* in_sizes, int n_in,
                              void* d_out, int out_size, void* d_ws, size_t ws_size,
                              hipStream_t stream) {
    const float* x = (const float*)d_in[0];
    const float* A = (const float*)d_in[1];
    const float* theta = (const float*)d_in[2];
    const float* W = (const float*)d_in[3];
    const float* b = (const float*)d_in[4];
    const int* kin = (const int*)d_in[5];
    float* out = (float*)d_out;

    // workspace layout (~128.2 MB)
    char* ws = (char*)d_ws;
    bf16_t* Sb = (bf16_t*)ws;                             // 32 MB
    bf16_t* Tb = (bf16_t*)(ws + (size_t)N * N * 2);       // 32 MB
    float* S2 = (float*)(ws + (size_t)N * N * 4);         // 64 MB
    float* dinv = (float*)(ws + (size_t)N * N * 8);       // 16 KB
    float* dinv2 = dinv + N;                              // 16 KB
    float* topv = dinv2 + N;                              // 64 KB
    int* topj = (int*)(topv + (size_t)N * 4);             // 64 KB

    k_rowsum_dinv<<<N, 256, 0, stream>>>(A, dinv);
    k_make_sbt<<<dim3(64, 64), 256, 0, stream>>>(A, dinv, Sb, Tb);
    k_gemm<<<dim3(32, 32), 256, 0, stream>>>(Sb, Tb, S2);
    k_rowsum2<<<N, 256, 0, stream>>>(A, S2, dinv, theta, dinv2);
    k_topk<<<N, 256, 0, stream>>>(A, S2, dinv, dinv2, theta, topv, topj);
    k_out<<<N, 64, 0, stream>>>(x, W, b, topv, topj, kin, out);
}

// Round 2
// 336.052 us; speedup vs baseline: 1.1070x; 1.1070x over previous
//
#include <hip/hip_runtime.h>
#include <hip/hip_bf16.h>
#include <float.h>
#include <math.h>

#define N 4096
#define DIN 64

typedef __bf16 bf16_t;
typedef __bf16 bf16x2 __attribute__((ext_vector_type(2)));
typedef __bf16 bf16x8 __attribute__((ext_vector_type(8)));
typedef float f32x4 __attribute__((ext_vector_type(4)));

// ---------- async global->LDS, 16B per lane ----------
__device__ __forceinline__ void gload16(const void* g, void* l) {
    __builtin_amdgcn_global_load_lds((const __attribute__((address_space(1))) void*)g,
                                     (__attribute__((address_space(3))) void*)l,
                                     16, 0, 0);
}

__device__ __forceinline__ float block_reduce_sum(float s) {
    __shared__ float red[4];
    #pragma unroll
    for (int off = 32; off; off >>= 1) s += __shfl_down(s, off);
    if ((threadIdx.x & 63) == 0) red[threadIdx.x >> 6] = s;
    __syncthreads();
    return red[0] + red[1] + red[2] + red[3];
}

// ---------- K1: rowsums of A -> dinv = 1/sqrt(d) ----------
__global__ __launch_bounds__(256) void k_rowsum_dinv(const float* __restrict__ A,
                                                     float* __restrict__ dinv) {
    int row = blockIdx.x, tid = threadIdx.x;
    const float4* a4 = (const float4*)(A + (size_t)row * N);
    float s = 0.f;
    for (int j = tid; j < N / 4; j += 256) {
        float4 v = a4[j];
        s += v.x + v.y + v.z + v.w;
    }
    float tot = block_reduce_sum(s);
    if (tid == 0) dinv[row] = rsqrtf(tot);
}

// ---------- K2: Sb = bf16(S), Tb = bf16(S^T)  (64x64 LDS transpose tiles) ----------
__global__ __launch_bounds__(256) void k_make_sbt(const float* __restrict__ A,
                                                  const float* __restrict__ dinv,
                                                  bf16_t* __restrict__ Sb,
                                                  bf16_t* __restrict__ Tb) {
    __shared__ float tile[64][65];
    int tid = threadIdx.x;
    int p = tid & 31;   // column-pair index
    int tg = tid >> 5;  // 0..7
    int i0 = blockIdx.y * 64;
    int j0 = blockIdx.x * 64;
    float dj0 = dinv[j0 + 2 * p];
    float dj1 = dinv[j0 + 2 * p + 1];
    #pragma unroll
    for (int rr = 0; rr < 8; rr++) {
        int r = tg + 8 * rr;
        int row = i0 + r;
        float di = dinv[row];
        float2 av = *(const float2*)(A + (size_t)row * N + j0 + 2 * p);
        float v0 = av.x * di * dj0;
        float v1 = av.y * di * dj1;
        bf16x2 bv;
        bv[0] = (bf16_t)v0;
        bv[1] = (bf16_t)v1;
        *(bf16x2*)(Sb + (size_t)row * N + j0 + 2 * p) = bv;
        tile[r][2 * p] = v0;
        tile[r][2 * p + 1] = v1;
    }
    __syncthreads();
    #pragma unroll
    for (int cc = 0; cc < 8; cc++) {
        int c = tg + 8 * cc;
        int gj = j0 + c;
        bf16x2 bv;
        bv[0] = (bf16_t)tile[2 * p][c];
        bv[1] = (bf16_t)tile[2 * p + 1][c];
        *(bf16x2*)(Tb + (size_t)gj * N + i0 + 2 * p) = bv;
    }
}

// ---------- K3: S2 = Sb @ Sb^T(Tb); epilogue writes P = t1*S2 + t0*S + I (fp32) ----------
// LDS layout: XOR-swizzled k-chunks. Slot (row, qs) holds global k-chunk
// q = qs ^ ((row>>1)&3). Staging lanes still cover one contiguous 64B line per
// row-group (coalesced, global_load_lds-compatible); ds_read_b128 fragment
// reads become 2-way bank aliasing (free) instead of 8-way.
__global__ __launch_bounds__(256) void k_gemm(const bf16_t* __restrict__ Sb,
                                              const bf16_t* __restrict__ Tb,
                                              const float* __restrict__ A,
                                              const float* __restrict__ dinv,
                                              const float* __restrict__ theta,
                                              float* __restrict__ P) {
    __shared__ bf16_t As[128 * 32];
    __shared__ bf16_t Bs[128 * 32];
    int tid = threadIdx.x;
    int lane = tid & 63;
    int wave = tid >> 6;
    int wr = wave >> 1, wc = wave & 1;
    int bi = blockIdx.x, bj = blockIdx.y;

    // staging: thread t -> LDS slot (row = t>>2 [+64 for stage 1], qslot = t&3)
    // global k-chunk q = (t&3) ^ ((t>>3)&3)  (same formula for both stages)
    int qoff = ((tid & 3) ^ ((tid >> 3) & 3)) * 8;
    int row0 = tid >> 2;
    const bf16_t* Ag0 = Sb + (size_t)(bi * 128 + row0) * N + qoff;
    const bf16_t* Ag1 = Sb + (size_t)(bi * 128 + 64 + row0) * N + qoff;
    const bf16_t* Bg0 = Tb + (size_t)(bj * 128 + row0) * N + qoff;
    const bf16_t* Bg1 = Tb + (size_t)(bj * 128 + 64 + row0) * N + qoff;
    bf16_t* Al0 = As + tid * 8;
    bf16_t* Al1 = As + (tid + 256) * 8;
    bf16_t* Bl0 = Bs + tid * 8;
    bf16_t* Bl1 = Bs + (tid + 256) * 8;

    f32x4 acc[4][4];
    f32x4 z = {0.f, 0.f, 0.f, 0.f};
    #pragma unroll
    for (int i = 0; i < 4; i++)
        #pragma unroll
        for (int j = 0; j < 4; j++) acc[i][j] = z;

    int r = lane & 15, q = lane >> 4;
    int qs = q ^ ((r >> 1) & 3);  // swizzle invariant under +16/+64 row offsets
    int aoff = (wr * 64 + r) * 32 + qs * 8;
    int boff = (wc * 64 + r) * 32 + qs * 8;

    for (int k0 = 0; k0 < N; k0 += 32) {
        __syncthreads();
        gload16(Ag0 + k0, Al0);
        gload16(Ag1 + k0, Al1);
        gload16(Bg0 + k0, Bl0);
        gload16(Bg1 + k0, Bl1);
        __syncthreads();
        bf16x8 af[4], bfr[4];
        #pragma unroll
        for (int mi = 0; mi < 4; mi++) af[mi] = *(const bf16x8*)(As + aoff + mi * 16 * 32);
        #pragma unroll
        for (int ni = 0; ni < 4; ni++) bfr[ni] = *(const bf16x8*)(Bs + boff + ni * 16 * 32);
        #pragma unroll
        for (int mi = 0; mi < 4; mi++)
            #pragma unroll
            for (int ni = 0; ni < 4; ni++)
                acc[mi][ni] = __builtin_amdgcn_mfma_f32_16x16x32_bf16(af[mi], bfr[ni],
                                                                      acc[mi][ni], 0, 0, 0);
    }

    // Epilogue: P_ij = t1*S2_ij + t0*A_ij*dinv_i*dinv_j + (i==j)
    // C/D layout: col = lane&15, row = (lane>>4)*4 + reg   [m89-verified]
    float t0 = 1.f / (1.f + expf(-theta[0]));
    float t1 = 1.f / (1.f + expf(-theta[1]));
    int col = lane & 15, row4 = (lane >> 4) * 4;
    #pragma unroll
    for (int mi = 0; mi < 4; mi++) {
        int gi0 = bi * 128 + wr * 64 + mi * 16 + row4;
        float di_[4];
        #pragma unroll
        for (int rr = 0; rr < 4; rr++) di_[rr] = dinv[gi0 + rr];
        #pragma unroll
        for (int ni = 0; ni < 4; ni++) {
            int gj = bj * 128 + wc * 64 + ni * 16 + col;
            float djv = dinv[gj];
            #pragma unroll
            for (int rr = 0; rr < 4; rr++) {
                int gi = gi0 + rr;
                float av = A[(size_t)gi * N + gj];
                float p = t1 * acc[mi][ni][rr] + t0 * av * di_[rr] * djv +
                          ((gi == gj) ? 1.f : 0.f);
                P[(size_t)gi * N + gj] = p;
            }
        }
    }
}

// ---------- K4: rowsums of P -> dinv2 ----------
__global__ __launch_bounds__(256) void k_rowsum2(const float* __restrict__ P,
                                                 float* __restrict__ dinv2) {
    int row = blockIdx.x, tid = threadIdx.x;
    const float4* p4 = (const float4*)(P + (size_t)row * N);
    float s = 0.f;
    for (int j = tid; j < N / 4; j += 256) {
        float4 v = p4[j];
        s += v.x + v.y + v.z + v.w;
    }
    float tot = block_reduce_sum(s);
    if (tid == 0) dinv2[row] = rsqrtf(tot);
}

// ---------- K5: per-row top-4 of P_ij*dinv2_j (ties->lower j) + fused output ----------
__device__ __forceinline__ bool better(float v1, int j1, float v2, int j2) {
    return v1 > v2 || (v1 == v2 && j1 < j2);
}
__device__ __forceinline__ void ins4(float v, int j, float bv[4], int bj[4]) {
    if (!better(v, j, bv[3], bj[3])) return;
    bv[3] = v; bj[3] = j;
    if (better(bv[3], bj[3], bv[2], bj[2])) {
        float tv = bv[2]; int tj = bj[2]; bv[2] = bv[3]; bj[2] = bj[3]; bv[3] = tv; bj[3] = tj;
    }
    if (better(bv[2], bj[2], bv[1], bj[1])) {
        float tv = bv[1]; int tj = bj[1]; bv[1] = bv[2]; bj[1] = bj[2]; bv[2] = tv; bj[2] = tj;
    }
    if (better(bv[1], bj[1], bv[0], bj[0])) {
        float tv = bv[0]; int tj = bj[0]; bv[0] = bv[1]; bj[0] = bj[1]; bv[1] = tv; bj[1] = tj;
    }
}

__global__ __launch_bounds__(256) void k_topk_out(const float* __restrict__ P,
                                                  const float* __restrict__ dinv2,
                                                  const float* __restrict__ x,
                                                  const float* __restrict__ W,
                                                  const float* __restrict__ bvec,
                                                  const int* __restrict__ kin,
                                                  float* __restrict__ out) {
    int row = blockIdx.x, tid = threadIdx.x;
    const float4* p4 = (const float4*)(P + (size_t)row * N);
    const float4* dd4 = (const float4*)dinv2;

    float bv[4] = {-FLT_MAX, -FLT_MAX, -FLT_MAX, -FLT_MAX};
    int bj[4] = {N, N, N, N};

    for (int qi = tid; qi < N / 4; qi += 256) {
        float4 pv = p4[qi], ddv = dd4[qi];
        int j = 4 * qi;
        ins4(pv.x * ddv.x, j + 0, bv, bj);
        ins4(pv.y * ddv.y, j + 1, bv, bj);
        ins4(pv.z * ddv.z, j + 2, bv, bj);
        ins4(pv.w * ddv.w, j + 3, bv, bj);
    }

    __shared__ float svv[1024];
    __shared__ int sjj[1024];
    __shared__ float y[DIN];
    #pragma unroll
    for (int c = 0; c < 4; c++) { svv[tid * 4 + c] = bv[c]; sjj[tid * 4 + c] = bj[c]; }
    for (int s = 128; s > 0; s >>= 1) {
        __syncthreads();
        if (tid < s) {
            #pragma unroll
            for (int c = 0; c < 4; c++) ins4(svv[(tid + s) * 4 + c], sjj[(tid + s) * 4 + c], bv, bj);
            #pragma unroll
            for (int c = 0; c < 4; c++) { svv[tid * 4 + c] = bv[c]; sjj[tid * 4 + c] = bj[c]; }
        }
    }
    __syncthreads();

    // fused: y = S_masked_row @ x  (S value = dinv2_i * (P_ij*dinv2_j))
    int kk = kin[0];
    if (kk > 4) kk = 4;
    if (kk < 0) kk = 0;
    if (tid < DIN) {
        float sc = dinv2[row];
        float acc = 0.f;
        for (int c = 0; c < kk; c++)
            acc += sc * svv[c] * x[(size_t)sjj[c] * DIN + tid];
        y[tid] = acc;
    }
    __syncthreads();
    // out = y @ W^T + b
    if (tid < DIN) {
        const float4* w4 = (const float4*)(W + (size_t)tid * DIN);
        const float4* y4 = (const float4*)y;
        float o = bvec[tid];
        #pragma unroll
        for (int d = 0; d < DIN / 4; d++) {
            float4 wv = w4[d], yv = y4[d];
            o += wv.x * yv.x + wv.y * yv.y + wv.z * yv.z + wv.w * yv.w;
        }
        out[(size_t)row * DIN + tid] = o;
    }
}

extern "C" void kernel_launch(void* const* d_in, const int* in_sizes, int n_in,
                              void* d_out, int out_size, void* d_ws, size_t ws_size,
                              hipStream_t stream) {
    const float* x = (const float*)d_in[0];
    const float* A = (const float*)d_in[1];
    const float* theta = (const float*)d_in[2];
    const float* W = (const float*)d_in[3];
    const float* b = (const float*)d_in[4];
    const int* kin = (const int*)d_in[5];
    float* out = (float*)d_out;

    // workspace layout (~128 MB)
    char* ws = (char*)d_ws;
    bf16_t* Sb = (bf16_t*)ws;                             // 32 MB
    bf16_t* Tb = (bf16_t*)(ws + (size_t)N * N * 2);       // 32 MB
    float* P = (float*)(ws + (size_t)N * N * 4);          // 64 MB
    float* dinv = (float*)(ws + (size_t)N * N * 8);       // 16 KB
    float* dinv2 = dinv + N;                              // 16 KB

    k_rowsum_dinv<<<N, 256, 0, stream>>>(A, dinv);
    k_make_sbt<<<dim3(64, 64), 256, 0, stream>>>(A, dinv, Sb, Tb);
    k_gemm<<<dim3(32, 32), 256, 0, stream>>>(Sb, Tb, A, dinv, theta, P);
    k_rowsum2<<<N, 256, 0, stream>>>(P, dinv2);
    k_topk_out<<<N, 256, 0, stream>>>(P, dinv2, x, W, b, kin, out);
}

// Round 3
// 297.015 us; speedup vs baseline: 1.2525x; 1.1314x over previous
//
#include <hip/hip_runtime.h>
#include <hip/hip_bf16.h>
#include <float.h>
#include <math.h>

#define N 4096
#define DIN 64

typedef signed char i8_t;
typedef signed char i8x4 __attribute__((ext_vector_type(4)));
typedef int i32x4 __attribute__((ext_vector_type(4)));

// ---------- async global->LDS, 16B per lane ----------
__device__ __forceinline__ void gload16(const void* g, void* l) {
    __builtin_amdgcn_global_load_lds((const __attribute__((address_space(1))) void*)g,
                                     (__attribute__((address_space(3))) void*)l,
                                     16, 0, 0);
}

__device__ __forceinline__ float block_reduce_sum(float s) {
    __shared__ float red[4];
    #pragma unroll
    for (int off = 32; off; off >>= 1) s += __shfl_down(s, off);
    if ((threadIdx.x & 63) == 0) red[threadIdx.x >> 6] = s;
    __syncthreads();
    return red[0] + red[1] + red[2] + red[3];
}

// ---------- K0: init accumulators (ws is poisoned 0xAA before every launch) ----------
__global__ __launch_bounds__(256) void k_init(float* __restrict__ rowsumP,
                                              int* __restrict__ dmax_i) {
    int g = blockIdx.x * 256 + threadIdx.x;
    rowsumP[g] = 0.f;
    if (g == 0) *dmax_i = 0;  // all dinv > 0 -> any __float_as_int(dinv) wins atomicMax
}

// ---------- K1: rowsums of A -> dinv = 1/sqrt(d); dmax = max(dinv) ----------
__global__ __launch_bounds__(256) void k_rowsum_dinv(const float* __restrict__ A,
                                                     float* __restrict__ dinv,
                                                     int* __restrict__ dmax_i) {
    int row = blockIdx.x, tid = threadIdx.x;
    const float4* a4 = (const float4*)(A + (size_t)row * N);
    float s = 0.f;
    for (int j = tid; j < N / 4; j += 256) {
        float4 v = a4[j];
        s += v.x + v.y + v.z + v.w;
    }
    float tot = block_reduce_sum(s);
    if (tid == 0) {
        float v = rsqrtf(tot);
        dinv[row] = v;
        atomicMax(dmax_i, __float_as_int(v));  // positive floats order-match ints
    }
}

// ---------- K2: Sq = i8(S), Tq = i8(S^T); q = rint(S * 127/dmax^2), S in [0,dmax^2) ----------
__global__ __launch_bounds__(256) void k_make_sqt(const float* __restrict__ A,
                                                  const float* __restrict__ dinv,
                                                  const int* __restrict__ dmax_i,
                                                  i8_t* __restrict__ Sq,
                                                  i8_t* __restrict__ Tq) {
    __shared__ float tile[64][65];
    int tid = threadIdx.x;
    int c4 = tid & 15;   // column group (4 cols)
    int rg = tid >> 4;   // 0..15
    int i0 = blockIdx.y * 64;
    int j0 = blockIdx.x * 64;
    float dmax = __int_as_float(*dmax_i);
    float sinv = 127.0f / (dmax * dmax);
    float4 dj = *(const float4*)(dinv + j0 + 4 * c4);
    #pragma unroll
    for (int rr = 0; rr < 4; rr++) {
        int r = rg + 16 * rr;
        int row = i0 + r;
        float di = dinv[row];
        float4 av = *(const float4*)(A + (size_t)row * N + j0 + 4 * c4);
        float s0 = av.x * di * dj.x, s1 = av.y * di * dj.y;
        float s2 = av.z * di * dj.z, s3 = av.w * di * dj.w;
        i8x4 qv;
        qv[0] = (i8_t)(int)fminf(rintf(s0 * sinv), 127.f);
        qv[1] = (i8_t)(int)fminf(rintf(s1 * sinv), 127.f);
        qv[2] = (i8_t)(int)fminf(rintf(s2 * sinv), 127.f);
        qv[3] = (i8_t)(int)fminf(rintf(s3 * sinv), 127.f);
        *(i8x4*)(Sq + (size_t)row * N + j0 + 4 * c4) = qv;
        tile[r][4 * c4 + 0] = s0;
        tile[r][4 * c4 + 1] = s1;
        tile[r][4 * c4 + 2] = s2;
        tile[r][4 * c4 + 3] = s3;
    }
    __syncthreads();
    #pragma unroll
    for (int cc = 0; cc < 4; cc++) {
        int c = rg + 16 * cc;
        int gj = j0 + c;
        i8x4 qv;
        #pragma unroll
        for (int u = 0; u < 4; u++)
            qv[u] = (i8_t)(int)fminf(rintf(tile[4 * c4 + u][c] * sinv), 127.f);
        *(i8x4*)(Tq + (size_t)gj * N + i0 + 4 * c4) = qv;
    }
}

// ---------- K3: S2i = Sq @ Sq^T(Tq) int8->int32 exact; epilogue P = t1*s^2*S2i + t0*S + I,
//             plus fused rowsum(P) via shfl-reduce + atomicAdd ----------
// LDS: XOR-swizzled 16B k-chunks (slot qs holds global chunk qs^((row>>1)&3)).
__global__ __launch_bounds__(256) void k_gemm(const i8_t* __restrict__ Sq,
                                              const i8_t* __restrict__ Tq,
                                              const float* __restrict__ A,
                                              const float* __restrict__ dinv,
                                              const int* __restrict__ dmax_i,
                                              const float* __restrict__ theta,
                                              float* __restrict__ P,
                                              float* __restrict__ rowsumP) {
    __shared__ i8_t As[128 * 64];
    __shared__ i8_t Bs[128 * 64];
    int tid = threadIdx.x;
    int lane = tid & 63;
    int wave = tid >> 6;
    int wr = wave >> 1, wc = wave & 1;
    int bi = blockIdx.x, bj = blockIdx.y;

    // staging: thread t -> slot (row = t>>2 [+64], qslot = t&3); 16B chunks
    // global chunk = (t&3) ^ ((t>>3)&3); per 4-thread group covers one 64B line
    int qoff = ((tid & 3) ^ ((tid >> 3) & 3)) * 16;
    int row0 = tid >> 2;
    const i8_t* Ag0 = Sq + (size_t)(bi * 128 + row0) * N + qoff;
    const i8_t* Ag1 = Sq + (size_t)(bi * 128 + 64 + row0) * N + qoff;
    const i8_t* Bg0 = Tq + (size_t)(bj * 128 + row0) * N + qoff;
    const i8_t* Bg1 = Tq + (size_t)(bj * 128 + 64 + row0) * N + qoff;
    i8_t* Al0 = As + tid * 16;
    i8_t* Al1 = As + (tid + 256) * 16;
    i8_t* Bl0 = Bs + tid * 16;
    i8_t* Bl1 = Bs + (tid + 256) * 16;

    i32x4 acc[4][4];
    i32x4 z = {0, 0, 0, 0};
    #pragma unroll
    for (int i = 0; i < 4; i++)
        #pragma unroll
        for (int j = 0; j < 4; j++) acc[i][j] = z;

    int r = lane & 15, q = lane >> 4;
    int qs = q ^ ((r >> 1) & 3);  // fragment-read swizzle (2-way bank alias = free)
    int aoff = (wr * 64 + r) * 64 + qs * 16;
    int boff = (wc * 64 + r) * 64 + qs * 16;

    for (int k0 = 0; k0 < N; k0 += 64) {
        __syncthreads();
        gload16(Ag0 + k0, Al0);
        gload16(Ag1 + k0, Al1);
        gload16(Bg0 + k0, Bl0);
        gload16(Bg1 + k0, Bl1);
        __syncthreads();
        i32x4 af[4], bfr[4];
        #pragma unroll
        for (int mi = 0; mi < 4; mi++) af[mi] = *(const i32x4*)(As + aoff + mi * 16 * 64);
        #pragma unroll
        for (int ni = 0; ni < 4; ni++) bfr[ni] = *(const i32x4*)(Bs + boff + ni * 16 * 64);
        #pragma unroll
        for (int mi = 0; mi < 4; mi++)
            #pragma unroll
            for (int ni = 0; ni < 4; ni++)
                acc[mi][ni] = __builtin_amdgcn_mfma_i32_16x16x64_i8(af[mi], bfr[ni],
                                                                    acc[mi][ni], 0, 0, 0);
    }

    // Epilogue: P_ij = t1*(acc*s^2) + t0*A_ij*dinv_i*dinv_j + (i==j); rowsum via atomics
    // C/D layout: col = lane&15, row = (lane>>4)*4 + reg   [m89-verified, dtype-indep]
    float dmax = __int_as_float(*dmax_i);
    float sq = dmax * dmax / 127.0f;
    float s2 = sq * sq;
    float t0 = 1.f / (1.f + expf(-theta[0]));
    float t1 = 1.f / (1.f + expf(-theta[1]));
    float t1s2 = t1 * s2;
    int col = lane & 15, row4 = (lane >> 4) * 4;
    #pragma unroll
    for (int mi = 0; mi < 4; mi++) {
        int gi0 = bi * 128 + wr * 64 + mi * 16 + row4;
        float di_[4];
        #pragma unroll
        for (int rr = 0; rr < 4; rr++) di_[rr] = dinv[gi0 + rr];
        float rsum[4] = {0.f, 0.f, 0.f, 0.f};
        #pragma unroll
        for (int ni = 0; ni < 4; ni++) {
            int gj = bj * 128 + wc * 64 + ni * 16 + col;
            float djv = dinv[gj];
            #pragma unroll
            for (int rr = 0; rr < 4; rr++) {
                int gi = gi0 + rr;
                float av = A[(size_t)gi * N + gj];
                float p = t1s2 * (float)acc[mi][ni][rr] + t0 * av * di_[rr] * djv +
                          ((gi == gj) ? 1.f : 0.f);
                P[(size_t)gi * N + gj] = p;
                rsum[rr] += p;
            }
        }
        #pragma unroll
        for (int rr = 0; rr < 4; rr++) {
            float v = rsum[rr];
            v += __shfl_xor(v, 1);
            v += __shfl_xor(v, 2);
            v += __shfl_xor(v, 4);
            v += __shfl_xor(v, 8);
            if ((lane & 15) == 0) atomicAdd(&rowsumP[gi0 + rr], v);
        }
    }
}

// ---------- K4: dinv2 = rsqrt(rowsumP) ----------
__global__ __launch_bounds__(256) void k_dinv2(const float* __restrict__ rowsumP,
                                               float* __restrict__ dinv2) {
    int g = blockIdx.x * 256 + threadIdx.x;
    dinv2[g] = rsqrtf(rowsumP[g]);
}

// ---------- K5: per-row top-4 of P_ij*dinv2_j (ties->lower j) + fused output ----------
__device__ __forceinline__ bool better(float v1, int j1, float v2, int j2) {
    return v1 > v2 || (v1 == v2 && j1 < j2);
}
__device__ __forceinline__ void ins4(float v, int j, float bv[4], int bj[4]) {
    if (!better(v, j, bv[3], bj[3])) return;
    bv[3] = v; bj[3] = j;
    if (better(bv[3], bj[3], bv[2], bj[2])) {
        float tv = bv[2]; int tj = bj[2]; bv[2] = bv[3]; bj[2] = bj[3]; bv[3] = tv; bj[3] = tj;
    }
    if (better(bv[2], bj[2], bv[1], bj[1])) {
        float tv = bv[1]; int tj = bj[1]; bv[1] = bv[2]; bj[1] = bj[2]; bv[2] = tv; bj[2] = tj;
    }
    if (better(bv[1], bj[1], bv[0], bj[0])) {
        float tv = bv[0]; int tj = bj[0]; bv[0] = bv[1]; bj[0] = bj[1]; bv[1] = tv; bj[1] = tj;
    }
}

__global__ __launch_bounds__(256) void k_topk_out(const float* __restrict__ P,
                                                  const float* __restrict__ dinv2,
                                                  const float* __restrict__ x,
                                                  const float* __restrict__ W,
                                                  const float* __restrict__ bvec,
                                                  const int* __restrict__ kin,
                                                  float* __restrict__ out) {
    int row = blockIdx.x, tid = threadIdx.x;
    const float4* p4 = (const float4*)(P + (size_t)row * N);
    const float4* dd4 = (const float4*)dinv2;

    float bv[4] = {-FLT_MAX, -FLT_MAX, -FLT_MAX, -FLT_MAX};
    int bj[4] = {N, N, N, N};

    for (int qi = tid; qi < N / 4; qi += 256) {
        float4 pv = p4[qi], ddv = dd4[qi];
        int j = 4 * qi;
        ins4(pv.x * ddv.x, j + 0, bv, bj);
        ins4(pv.y * ddv.y, j + 1, bv, bj);
        ins4(pv.z * ddv.z, j + 2, bv, bj);
        ins4(pv.w * ddv.w, j + 3, bv, bj);
    }

    __shared__ float svv[1024];
    __shared__ int sjj[1024];
    __shared__ float y[DIN];
    #pragma unroll
    for (int c = 0; c < 4; c++) { svv[tid * 4 + c] = bv[c]; sjj[tid * 4 + c] = bj[c]; }
    for (int s = 128; s > 0; s >>= 1) {
        __syncthreads();
        if (tid < s) {
            #pragma unroll
            for (int c = 0; c < 4; c++) ins4(svv[(tid + s) * 4 + c], sjj[(tid + s) * 4 + c], bv, bj);
            #pragma unroll
            for (int c = 0; c < 4; c++) { svv[tid * 4 + c] = bv[c]; sjj[tid * 4 + c] = bj[c]; }
        }
    }
    __syncthreads();

    // fused: y = S_masked_row @ x  (S value = dinv2_i * (P_ij*dinv2_j))
    int kk = kin[0];
    if (kk > 4) kk = 4;
    if (kk < 0) kk = 0;
    if (tid < DIN) {
        float sc = dinv2[row];
        float acc = 0.f;
        for (int c = 0; c < kk; c++)
            acc += sc * svv[c] * x[(size_t)sjj[c] * DIN + tid];
        y[tid] = acc;
    }
    __syncthreads();
    // out = y @ W^T + b
    if (tid < DIN) {
        const float4* w4 = (const float4*)(W + (size_t)tid * DIN);
        const float4* y4 = (const float4*)y;
        float o = bvec[tid];
        #pragma unroll
        for (int d = 0; d < DIN / 4; d++) {
            float4 wv = w4[d], yv = y4[d];
            o += wv.x * yv.x + wv.y * yv.y + wv.z * yv.z + wv.w * yv.w;
        }
        out[(size_t)row * DIN + tid] = o;
    }
}

extern "C" void kernel_launch(void* const* d_in, const int* in_sizes, int n_in,
                              void* d_out, int out_size, void* d_ws, size_t ws_size,
                              hipStream_t stream) {
    const float* x = (const float*)d_in[0];
    const float* A = (const float*)d_in[1];
    const float* theta = (const float*)d_in[2];
    const float* W = (const float*)d_in[3];
    const float* b = (const float*)d_in[4];
    const int* kin = (const int*)d_in[5];
    float* out = (float*)d_out;

    // workspace layout (~96 MB)
    char* ws = (char*)d_ws;
    i8_t* Sq = (i8_t*)ws;                                  // 16 MB
    i8_t* Tq = (i8_t*)(ws + (size_t)N * N);                // 16 MB
    float* P = (float*)(ws + (size_t)N * N * 2);           // 64 MB
    float* dinv = (float*)(ws + (size_t)N * N * 6);        // 16 KB
    float* dinv2 = dinv + N;                               // 16 KB
    float* rowsumP = dinv2 + N;                            // 16 KB
    int* dmax_i = (int*)(rowsumP + N);                     // 4 B

    k_init<<<N / 256, 256, 0, stream>>>(rowsumP, dmax_i);
    k_rowsum_dinv<<<N, 256, 0, stream>>>(A, dinv, dmax_i);
    k_make_sqt<<<dim3(64, 64), 256, 0, stream>>>(A, dinv, dmax_i, Sq, Tq);
    k_gemm<<<dim3(32, 32), 256, 0, stream>>>(Sq, Tq, A, dinv, dmax_i, theta, P, rowsumP);
    k_dinv2<<<N / 256, 256, 0, stream>>>(rowsumP, dinv2);
    k_topk_out<<<N, 256, 0, stream>>>(P, dinv2, x, W, b, kin, out);
}

// Round 5
// 276.935 us; speedup vs baseline: 1.3433x; 1.0725x over previous
//
#include <hip/hip_runtime.h>
#include <hip/hip_bf16.h>
#include <float.h>
#include <math.h>

#define N 4096
#define DIN 64

typedef signed char i8_t;
typedef signed char i8x4 __attribute__((ext_vector_type(4)));
typedef int i32x4 __attribute__((ext_vector_type(4)));
typedef float f32x4 __attribute__((ext_vector_type(4)));

// ---------- async global->LDS, 16B per lane ----------
__device__ __forceinline__ void gload16(const void* g, void* l) {
    __builtin_amdgcn_global_load_lds((const __attribute__((address_space(1))) void*)g,
                                     (__attribute__((address_space(3))) void*)l,
                                     16, 0, 0);
}

__device__ __forceinline__ float block_reduce_sum(float s) {
    __shared__ float red[4];
    #pragma unroll
    for (int off = 32; off; off >>= 1) s += __shfl_down(s, off);
    if ((threadIdx.x & 63) == 0) red[threadIdx.x >> 6] = s;
    __syncthreads();
    return red[0] + red[1] + red[2] + red[3];
}

// ---------- top-4 insertion with tie -> lower index ----------
__device__ __forceinline__ bool better(float v1, int j1, float v2, int j2) {
    return v1 > v2 || (v1 == v2 && j1 < j2);
}
__device__ __forceinline__ void ins4(float v, int j, float bv[4], int bj[4]) {
    if (!better(v, j, bv[3], bj[3])) return;
    bv[3] = v; bj[3] = j;
    if (better(bv[3], bj[3], bv[2], bj[2])) {
        float tv = bv[2]; int tj = bj[2]; bv[2] = bv[3]; bj[2] = bj[3]; bv[3] = tv; bj[3] = tj;
    }
    if (better(bv[2], bj[2], bv[1], bj[1])) {
        float tv = bv[1]; int tj = bj[1]; bv[1] = bv[2]; bj[1] = bj[2]; bv[2] = tv; bj[2] = tj;
    }
    if (better(bv[1], bj[1], bv[0], bj[0])) {
        float tv = bv[0]; int tj = bj[0]; bv[0] = bv[1]; bj[0] = bj[1]; bv[1] = tv; bj[1] = tj;
    }
}

// ---------- K1: rowsums of A -> dinv = 1/sqrt(d); also zero rowsumP ----------
__global__ __launch_bounds__(256) void k_rowsum_dinv(const float* __restrict__ A,
                                                     float* __restrict__ dinv,
                                                     float* __restrict__ rowsumP) {
    int row = blockIdx.x, tid = threadIdx.x;
    const float4* a4 = (const float4*)(A + (size_t)row * N);
    float s = 0.f;
    for (int j = tid; j < N / 4; j += 256) {
        float4 v = a4[j];
        s += v.x + v.y + v.z + v.w;
    }
    float tot = block_reduce_sum(s);
    if (tid == 0) {
        dinv[row] = rsqrtf(tot);
        rowsumP[row] = 0.f;  // init for k_gemm's atomics (ws is poisoned pre-launch)
    }
}

// ---------- K2: dmax = max(dinv), single block ----------
__global__ __launch_bounds__(1024) void k_dmax(const float* __restrict__ dinv,
                                               float* __restrict__ dmaxf) {
    int t = threadIdx.x;
    float m = fmaxf(fmaxf(dinv[t], dinv[t + 1024]), fmaxf(dinv[t + 2048], dinv[t + 3072]));
    #pragma unroll
    for (int off = 32; off; off >>= 1) m = fmaxf(m, __shfl_down(m, off));
    __shared__ float red[16];
    if ((t & 63) == 0) red[t >> 6] = m;
    __syncthreads();
    if (t == 0) {
        float mm = red[0];
        #pragma unroll
        for (int i = 1; i < 16; i++) mm = fmaxf(mm, red[i]);
        *dmaxf = mm;
    }
}

// ---------- K3: Sq = i8(S), Tq = i8(S^T); q = rint(S * 127/dmax^2) ----------
__global__ __launch_bounds__(256) void k_make_sqt(const float* __restrict__ A,
                                                  const float* __restrict__ dinv,
                                                  const float* __restrict__ dmaxf,
                                                  i8_t* __restrict__ Sq,
                                                  i8_t* __restrict__ Tq) {
    __shared__ float tile[64][65];
    int tid = threadIdx.x;
    int c4 = tid & 15;   // column group (4 cols)
    int rg = tid >> 4;   // 0..15
    int i0 = blockIdx.y * 64;
    int j0 = blockIdx.x * 64;
    float dmax = *dmaxf;
    float sinv = 127.0f / (dmax * dmax);
    float4 dj = *(const float4*)(dinv + j0 + 4 * c4);
    #pragma unroll
    for (int rr = 0; rr < 4; rr++) {
        int r = rg + 16 * rr;
        int row = i0 + r;
        float di = dinv[row];
        float4 av = *(const float4*)(A + (size_t)row * N + j0 + 4 * c4);
        float s0 = av.x * di * dj.x, s1 = av.y * di * dj.y;
        float s2 = av.z * di * dj.z, s3 = av.w * di * dj.w;
        i8x4 qv;
        qv[0] = (i8_t)(int)fminf(rintf(s0 * sinv), 127.f);
        qv[1] = (i8_t)(int)fminf(rintf(s1 * sinv), 127.f);
        qv[2] = (i8_t)(int)fminf(rintf(s2 * sinv), 127.f);
        qv[3] = (i8_t)(int)fminf(rintf(s3 * sinv), 127.f);
        *(i8x4*)(Sq + (size_t)row * N + j0 + 4 * c4) = qv;
        tile[r][4 * c4 + 0] = s0;
        tile[r][4 * c4 + 1] = s1;
        tile[r][4 * c4 + 2] = s2;
        tile[r][4 * c4 + 3] = s3;
    }
    __syncthreads();
    #pragma unroll
    for (int cc = 0; cc < 4; cc++) {
        int c = rg + 16 * cc;
        int gj = j0 + c;
        i8x4 qv;
        #pragma unroll
        for (int u = 0; u < 4; u++)
            qv[u] = (i8_t)(int)fminf(rintf(tile[4 * c4 + u][c] * sinv), 127.f);
        *(i8x4*)(Tq + (size_t)gj * N + i0 + 4 * c4) = qv;
    }
}

// ---------- K4: int8 GEMM + fused epilogue:
//   p = t1*s^2*(QQ^T) + t0*s*Q + I  (never materialized to HBM)
//   rowsumP += per-row sums (atomics); per-(row,block) top-4 candidates -> candV/candJ
// LDS: XOR-swizzled 16B k-chunks for staging; pbuf[128][65] for the top-k scan.
__global__ __launch_bounds__(256) void k_gemm(const i8_t* __restrict__ Sq,
                                              const i8_t* __restrict__ Tq,
                                              const float* __restrict__ dmaxf,
                                              const float* __restrict__ theta,
                                              float* __restrict__ rowsumP,
                                              float* __restrict__ candV,
                                              int* __restrict__ candJ) {
    __shared__ i8_t As[128 * 64];
    __shared__ i8_t Bs[128 * 64];
    __shared__ float pbuf[128][65];  // half-tile (128 rows x 64 cols) per pass
    int tid = threadIdx.x;
    int lane = tid & 63;
    int wave = tid >> 6;
    int wr = wave >> 1, wc = wave & 1;
    int bi = blockIdx.x, bj = blockIdx.y;

    // staging: thread t -> slot (row = t>>2 [+64], qslot = t&3); 16B chunks
    int qoff = ((tid & 3) ^ ((tid >> 3) & 3)) * 16;
    int row0 = tid >> 2;
    const i8_t* Ag0 = Sq + (size_t)(bi * 128 + row0) * N + qoff;
    const i8_t* Ag1 = Sq + (size_t)(bi * 128 + 64 + row0) * N + qoff;
    const i8_t* Bg0 = Tq + (size_t)(bj * 128 + row0) * N + qoff;
    const i8_t* Bg1 = Tq + (size_t)(bj * 128 + 64 + row0) * N + qoff;
    i8_t* Al0 = As + tid * 16;
    i8_t* Al1 = As + (tid + 256) * 16;
    i8_t* Bl0 = Bs + tid * 16;
    i8_t* Bl1 = Bs + (tid + 256) * 16;

    i32x4 acc[4][4];
    i32x4 z = {0, 0, 0, 0};
    #pragma unroll
    for (int i = 0; i < 4; i++)
        #pragma unroll
        for (int j = 0; j < 4; j++) acc[i][j] = z;

    int r = lane & 15, q = lane >> 4;
    int qs = q ^ ((r >> 1) & 3);  // fragment-read swizzle (2-way = free)
    int aoff = (wr * 64 + r) * 64 + qs * 16;
    int boff = (wc * 64 + r) * 64 + qs * 16;

    for (int k0 = 0; k0 < N; k0 += 64) {
        __syncthreads();
        gload16(Ag0 + k0, Al0);
        gload16(Ag1 + k0, Al1);
        gload16(Bg0 + k0, Bl0);
        gload16(Bg1 + k0, Bl1);
        __syncthreads();
        i32x4 af[4], bfr[4];
        #pragma unroll
        for (int mi = 0; mi < 4; mi++) af[mi] = *(const i32x4*)(As + aoff + mi * 16 * 64);
        #pragma unroll
        for (int ni = 0; ni < 4; ni++) bfr[ni] = *(const i32x4*)(Bs + boff + ni * 16 * 64);
        #pragma unroll
        for (int mi = 0; mi < 4; mi++)
            #pragma unroll
            for (int ni = 0; ni < 4; ni++)
                acc[mi][ni] = __builtin_amdgcn_mfma_i32_16x16x64_i8(af[mi], bfr[ni],
                                                                    acc[mi][ni], 0, 0, 0);
    }

    // ---- epilogue: p in place of acc (bit_cast reuse, no VGPR spike) ----
    float dmax = *dmaxf;
    float sq = dmax * dmax / 127.0f;
    float t0 = 1.f / (1.f + expf(-theta[0]));
    float t1 = 1.f / (1.f + expf(-theta[1]));
    float t0s = t0 * sq;
    float t1s2 = t1 * sq * sq;
    int col = lane & 15, quad = lane >> 4;

    #pragma unroll
    for (int mi = 0; mi < 4; mi++) {
        int gi0 = bi * 128 + wr * 64 + mi * 16 + quad * 4;
        float rsum[4] = {0.f, 0.f, 0.f, 0.f};
        #pragma unroll
        for (int ni = 0; ni < 4; ni++) {
            int gj = bj * 128 + wc * 64 + ni * 16 + col;
            f32x4 pf;
            #pragma unroll
            for (int rr = 0; rr < 4; rr++) {
                int gi = gi0 + rr;
                float qv = (float)Sq[(size_t)gi * N + gj];  // t0 term from quantized S
                float p = t1s2 * (float)acc[mi][ni][rr] + t0s * qv + ((gi == gj) ? 1.f : 0.f);
                pf[rr] = p;
                rsum[rr] += p;
            }
            acc[mi][ni] = __builtin_bit_cast(i32x4, pf);  // store p back into acc regs
        }
        #pragma unroll
        for (int rr = 0; rr < 4; rr++) {
            float v = rsum[rr];
            v += __shfl_xor(v, 1);
            v += __shfl_xor(v, 2);
            v += __shfl_xor(v, 4);
            v += __shfl_xor(v, 8);
            if (col == 0) atomicAdd(&rowsumP[gi0 + rr], v);
        }
    }

    // ---- two-pass LDS round-trip + per-row top-4 scan ----
    float bv[4] = {-FLT_MAX, -FLT_MAX, -FLT_MAX, -FLT_MAX};
    int bjx[4] = {N, N, N, N};
    int srow = tid >> 1;        // scan row 0..127
    int shalf = tid & 1;        // which 32-col half this thread scans

    #pragma unroll
    for (int pass = 0; pass < 2; pass++) {
        if (wc == pass) {
            #pragma unroll
            for (int mi = 0; mi < 4; mi++) {
                int prow = wr * 64 + mi * 16 + quad * 4;
                #pragma unroll
                for (int ni = 0; ni < 4; ni++) {
                    f32x4 pf = __builtin_bit_cast(f32x4, acc[mi][ni]);
                    #pragma unroll
                    for (int rr = 0; rr < 4; rr++)
                        pbuf[prow + rr][ni * 16 + col] = pf[rr];
                }
            }
        }
        __syncthreads();
        int jbase = bj * 128 + pass * 64 + shalf * 32;
        for (int i = 0; i < 32; i++)
            ins4(pbuf[srow][shalf * 32 + i], jbase + i, bv, bjx);
        __syncthreads();
    }

    // merge partner (t^1 scanned the other 32-col halves), write 4 candidates/row
    float ov[4]; int oj[4];
    #pragma unroll
    for (int c = 0; c < 4; c++) { ov[c] = __shfl_xor(bv[c], 1); oj[c] = __shfl_xor(bjx[c], 1); }
    #pragma unroll
    for (int c = 0; c < 4; c++) ins4(ov[c], oj[c], bv, bjx);
    if (shalf == 0) {
        size_t base = ((size_t)(bi * 128 + srow) * 32 + bj) * 4;
        #pragma unroll
        for (int c = 0; c < 4; c++) { candV[base + c] = bv[c]; candJ[base + c] = bjx[c]; }
    }
}

// ---------- K5: dinv2 = rsqrt(rowsumP) ----------
__global__ __launch_bounds__(256) void k_dinv2(const float* __restrict__ rowsumP,
                                               float* __restrict__ dinv2) {
    int g = blockIdx.x * 256 + threadIdx.x;
    dinv2[g] = rsqrtf(rowsumP[g]);
}

// ---------- K6: per-row final top-4 (exact dinv2 scaling) + fused output ----------
// 128 candidates/row; 64 threads x 2 candidates each (NOT 4 -- that over-ran the
// row segment and fabricated indices from float bit patterns -> OOB fault in R4).
__global__ __launch_bounds__(64) void k_final(const float* __restrict__ candV,
                                              const int* __restrict__ candJ,
                                              const float* __restrict__ dinv2,
                                              const float* __restrict__ x,
                                              const float* __restrict__ W,
                                              const float* __restrict__ bvec,
                                              const int* __restrict__ kin,
                                              float* __restrict__ out) {
    int row = blockIdx.x, t = threadIdx.x;
    float2 cv = *(const float2*)(candV + (size_t)row * 128 + t * 2);
    int2 cj = *(const int2*)(candJ + (size_t)row * 128 + t * 2);
    float bv[4] = {-FLT_MAX, -FLT_MAX, -FLT_MAX, -FLT_MAX};
    int bj[4] = {N, N, N, N};
    ins4(cv.x * dinv2[cj.x], cj.x, bv, bj);
    ins4(cv.y * dinv2[cj.y], cj.y, bv, bj);
    // butterfly merge across 64 lanes (disjoint sets at every step)
    #pragma unroll
    for (int off = 1; off < 64; off <<= 1) {
        float ov[4]; int oj[4];
        #pragma unroll
        for (int c = 0; c < 4; c++) { ov[c] = __shfl_xor(bv[c], off); oj[c] = __shfl_xor(bj[c], off); }
        #pragma unroll
        for (int c = 0; c < 4; c++) ins4(ov[c], oj[c], bv, bj);
    }
    // all lanes now hold the row's global top-4 (value = P_ij*dinv2_j, idx = j)
    int kk = kin[0];
    if (kk > 4) kk = 4;
    if (kk < 0) kk = 0;
    float sc = dinv2[row];
    float y = 0.f;
    for (int c = 0; c < kk; c++)
        y += sc * bv[c] * x[(size_t)bj[c] * DIN + t];
    __shared__ float ys[DIN];
    ys[t] = y;
    __syncthreads();
    const float4* w4 = (const float4*)(W + (size_t)t * DIN);
    const float4* y4 = (const float4*)ys;
    float o = bvec[t];
    #pragma unroll
    for (int d = 0; d < DIN / 4; d++) {
        float4 wv = w4[d], yv = y4[d];
        o += wv.x * yv.x + wv.y * yv.y + wv.z * yv.z + wv.w * yv.w;
    }
    out[(size_t)row * DIN + t] = o;
}

extern "C" void kernel_launch(void* const* d_in, const int* in_sizes, int n_in,
                              void* d_out, int out_size, void* d_ws, size_t ws_size,
                              hipStream_t stream) {
    const float* x = (const float*)d_in[0];
    const float* A = (const float*)d_in[1];
    const float* theta = (const float*)d_in[2];
    const float* W = (const float*)d_in[3];
    const float* b = (const float*)d_in[4];
    const int* kin = (const int*)d_in[5];
    float* out = (float*)d_out;

    // workspace layout (~38 MB)
    char* ws = (char*)d_ws;
    i8_t* Sq = (i8_t*)ws;                                  // 16 MB
    i8_t* Tq = (i8_t*)(ws + (size_t)N * N);                // 16 MB
    float* candV = (float*)(ws + (size_t)N * N * 2);       // 2 MB
    int* candJ = (int*)(ws + (size_t)N * N * 2 + (size_t)N * 128 * 4);  // 2 MB
    float* dinv = (float*)(ws + (size_t)N * N * 2 + (size_t)N * 128 * 8);
    float* dinv2 = dinv + N;
    float* rowsumP = dinv2 + N;
    float* dmaxf = rowsumP + N;

    k_rowsum_dinv<<<N, 256, 0, stream>>>(A, dinv, rowsumP);
    k_dmax<<<1, 1024, 0, stream>>>(dinv, dmaxf);
    k_make_sqt<<<dim3(64, 64), 256, 0, stream>>>(A, dinv, dmaxf, Sq, Tq);
    k_gemm<<<dim3(32, 32), 256, 0, stream>>>(Sq, Tq, dmaxf, theta, rowsumP, candV, candJ);
    k_dinv2<<<N / 256, 256, 0, stream>>>(rowsumP, dinv2);
    k_final<<<N, 64, 0, stream>>>(candV, candJ, dinv2, x, W, b, kin, out);
}